// Round 1
// baseline (18712.451 us; speedup 1.0000x reference)
//
#include <hip/hip_runtime.h>
#include <math.h>

#define Bb 4
#define Ls 2048
#define Dd 1024
#define Hh 16
#define HDm 64
#define ML (Bb*Ls)   /* 8192 rows */

// ---------------------------------------------------------------------------
// NT GEMM, fp64 accumulate, fp64 output: C[m,n] = sum_k A[m,k]*B[n,k]
// M=8192, N=1024, K=1024. Tile 64x64, BK=16, 256 threads, 4x4 per thread.
// fp64 needed: logits have sigma~1.1e6; softmax tie-resolution vs the numpy
// (fp64) reference needs absolute logit error << 1, which fp32 cannot give.
// ---------------------------------------------------------------------------
__global__ __launch_bounds__(256) void gemm_nt_f64(
    const float* __restrict__ A, const float* __restrict__ B,
    double* __restrict__ C) {
  const int N = Dd, K = Dd;
  __shared__ float As[64][17];
  __shared__ float Bs[64][17];
  int tid = threadIdx.x;
  int tx = tid & 15, ty = tid >> 4;
  int bm = blockIdx.y * 64, bn = blockIdx.x * 64;
  double acc[4][4];
#pragma unroll
  for (int i = 0; i < 4; i++)
#pragma unroll
    for (int j = 0; j < 4; j++) acc[i][j] = 0.0;

  for (int k0 = 0; k0 < K; k0 += 16) {
#pragma unroll
    for (int i = 0; i < 4; i++) {
      int idx = tid + i * 256;
      int r = idx >> 4, c = idx & 15;
      As[r][c] = A[(size_t)(bm + r) * K + k0 + c];
      Bs[r][c] = B[(size_t)(bn + r) * K + k0 + c];
    }
    __syncthreads();
#pragma unroll
    for (int kk = 0; kk < 16; kk++) {
      double a[4], b[4];
#pragma unroll
      for (int i = 0; i < 4; i++) a[i] = (double)As[ty * 4 + i][kk];
#pragma unroll
      for (int j = 0; j < 4; j++) b[j] = (double)Bs[tx * 4 + j][kk];
#pragma unroll
      for (int i = 0; i < 4; i++)
#pragma unroll
        for (int j = 0; j < 4; j++)
          acc[i][j] = fma(a[i], b[j], acc[i][j]);
    }
    __syncthreads();
  }
#pragma unroll
  for (int i = 0; i < 4; i++) {
    size_t m = (size_t)(bm + ty * 4 + i);
#pragma unroll
    for (int j = 0; j < 4; j++) {
      int n = bn + tx * 4 + j;
      C[m * N + n] = acc[i][j];
    }
  }
}

// ---------------------------------------------------------------------------
// NT GEMM, fp32, optional bias: C[m,n] = sum_k A[m,k]*B[n,k] (+ bias[n])
// ---------------------------------------------------------------------------
__global__ __launch_bounds__(256) void gemm_nt_f32(
    const float* __restrict__ A, const float* __restrict__ B,
    const float* __restrict__ bias, float* __restrict__ C) {
  const int N = Dd, K = Dd;
  __shared__ float As[64][17];
  __shared__ float Bs[64][17];
  int tid = threadIdx.x;
  int tx = tid & 15, ty = tid >> 4;
  int bm = blockIdx.y * 64, bn = blockIdx.x * 64;
  float acc[4][4];
#pragma unroll
  for (int i = 0; i < 4; i++)
#pragma unroll
    for (int j = 0; j < 4; j++) acc[i][j] = 0.0f;

  for (int k0 = 0; k0 < K; k0 += 16) {
#pragma unroll
    for (int i = 0; i < 4; i++) {
      int idx = tid + i * 256;
      int r = idx >> 4, c = idx & 15;
      As[r][c] = A[(size_t)(bm + r) * K + k0 + c];
      Bs[r][c] = B[(size_t)(bn + r) * K + k0 + c];
    }
    __syncthreads();
#pragma unroll
    for (int kk = 0; kk < 16; kk++) {
      float a[4], b[4];
#pragma unroll
      for (int i = 0; i < 4; i++) a[i] = As[ty * 4 + i][kk];
#pragma unroll
      for (int j = 0; j < 4; j++) b[j] = Bs[tx * 4 + j][kk];
#pragma unroll
      for (int i = 0; i < 4; i++)
#pragma unroll
        for (int j = 0; j < 4; j++)
          acc[i][j] = fmaf(a[i], b[j], acc[i][j]);
    }
    __syncthreads();
  }
#pragma unroll
  for (int i = 0; i < 4; i++) {
    size_t m = (size_t)(bm + ty * 4 + i);
#pragma unroll
    for (int j = 0; j < 4; j++) {
      int n = bn + tx * 4 + j;
      float v = acc[i][j];
      if (bias) v += bias[n];
      C[m * N + n] = v;
    }
  }
}

// ---------------------------------------------------------------------------
// Attention: one block = (b, h, 2 query rows).
// energy fp64 (LDS 2x2048 doubles = 32KB), softmax gap in fp64 -> expf(fp32),
// write normalized probs to attn output, PV in fp32 into O (b,l,(h hd)).
// ---------------------------------------------------------------------------
__global__ __launch_bounds__(256) void attn_kernel(
    const double* __restrict__ Qd, const double* __restrict__ Kd,
    const float* __restrict__ Vf, float* __restrict__ attn,
    float* __restrict__ O) {
  __shared__ double qs[2][HDm];       // 1 KB
  __shared__ double es[2][Ls];        // 32 KB
  __shared__ double wred[4];
  __shared__ double rowmax[2], rowinv[2];
  __shared__ float pvp[2][2][64];     // [seg][row][col]

  int tid = threadIdx.x;
  int blk = blockIdx.x;                 // 65536 blocks
  int lt = blk & 1023;                  // L/2 = 1024 tiles
  int bh = blk >> 10;
  int h = bh & (Hh - 1);
  int b = bh >> 4;
  int l0 = lt * 2;

  // load the two q rows (fp64)
  if (tid < 128) {
    int r = tid >> 6, c = tid & 63;
    qs[r][c] = Qd[((size_t)b * Ls + l0 + r) * Dd + h * HDm + c];
  }
  __syncthreads();

  // energy: fp64 dot of q row with each k row, scaled by 1/8
  const double* Kbase = Kd + (size_t)b * Ls * Dd + h * HDm;
  for (int p = tid; p < 2 * Ls; p += 256) {
    int r = p >> 11, t = p & (Ls - 1);
    const double* kp = Kbase + (size_t)t * Dd;
    double s = 0.0;
#pragma unroll
    for (int c = 0; c < HDm; c++) s = fma(qs[r][c], kp[c], s);
    es[r][t] = s * 0.125;
  }
  __syncthreads();

  // row max (fp64), wave shuffle reduce
  int r = tid >> 7;        // 0..1
  int l1 = tid & 127;
  int wave = tid >> 6;
  {
    double m = -1e300;
    for (int t = l1; t < Ls; t += 128) m = fmax(m, es[r][t]);
#pragma unroll
    for (int off = 32; off; off >>= 1) {
      double o = __shfl_down(m, off);
      m = fmax(m, o);
    }
    if ((tid & 63) == 0) wred[wave] = m;
  }
  __syncthreads();
  if (tid < 2) rowmax[tid] = fmax(wred[tid * 2], wred[tid * 2 + 1]);
  __syncthreads();

  // exp(e - max): gap computed in fp64, exp in fp32 (gap is small), sum fp64
  {
    double mm = rowmax[r];
    double s = 0.0;
    for (int t = l1; t < Ls; t += 128) {
      float pf = expf((float)(es[r][t] - mm));
      es[r][t] = (double)pf;
      s += (double)pf;
    }
#pragma unroll
    for (int off = 32; off; off >>= 1) s += __shfl_down(s, off);
    if ((tid & 63) == 0) wred[wave] = s;
  }
  __syncthreads();
  if (tid < 2) rowinv[tid] = 1.0 / (wred[tid * 2] + wred[tid * 2 + 1]);
  __syncthreads();

  // normalize, write attention output, keep p in LDS for PV
  float* aout = attn + ((size_t)(b * Hh + h) * Ls + l0) * Ls;
  for (int p = tid; p < 2 * Ls; p += 256) {
    int rr = p >> 11, t = p & (Ls - 1);
    float pr = (float)(es[rr][t] * rowinv[rr]);
    es[rr][t] = (double)pr;
    aout[(size_t)rr * Ls + t] = pr;
  }
  __syncthreads();

  // PV: out[row, col] = sum_t p[row,t] * V[t, col]  (fp32)
  {
    int col = tid & 63;
    int rg = (tid >> 6) & 1;   // row
    int seg = tid >> 7;        // t-half
    const float* Vb = Vf + (size_t)b * Ls * Dd + h * HDm + col;
    float acc = 0.0f;
    int t0 = seg * 1024;
    for (int t = t0; t < t0 + 1024; t++)
      acc = fmaf((float)es[rg][t], Vb[(size_t)t * Dd], acc);
    pvp[seg][rg][col] = acc;
  }
  __syncthreads();
  if (tid < 128) {
    int row = tid >> 6, c = tid & 63;
    float v = pvp[0][row][c] + pvp[1][row][c];
    O[((size_t)b * Ls + l0 + row) * Dd + h * HDm + c] = v;
  }
}

// ---------------------------------------------------------------------------
extern "C" void kernel_launch(void* const* d_in, const int* in_sizes, int n_in,
                              void* d_out, int out_size, void* d_ws, size_t ws_size,
                              hipStream_t stream) {
  const float* query = (const float*)d_in[0];
  const float* key   = (const float*)d_in[1];
  const float* value = (const float*)d_in[2];
  const float* Wq    = (const float*)d_in[3];
  const float* Wk    = (const float*)d_in[4];
  const float* Wv    = (const float*)d_in[5];
  const float* Wo    = (const float*)d_in[6];
  const float* bo    = (const float*)d_in[7];

  float* out0 = (float*)d_out;                       // [B,L,D] = 8388608 floats
  float* attn = out0 + (size_t)ML * Dd;              // [B,H,L,L] = 268435456 floats

  // workspace: Qd (64MB f64) | Kd (64MB f64) | Vf (32MB f32) | Of (32MB f32)
  char* ws = (char*)d_ws;
  double* Qd = (double*)ws;
  double* Kd = (double*)(ws + (size_t)ML * Dd * 8);
  float*  Vf = (float*)(ws + (size_t)ML * Dd * 16);
  float*  Of = (float*)(ws + (size_t)ML * Dd * 16 + (size_t)ML * Dd * 4);

  dim3 gemm_grid(Dd / 64, ML / 64);   // (16, 128)
  gemm_nt_f64<<<gemm_grid, 256, 0, stream>>>(query, Wq, Qd);
  gemm_nt_f64<<<gemm_grid, 256, 0, stream>>>(key,   Wk, Kd);
  gemm_nt_f32<<<gemm_grid, 256, 0, stream>>>(value, Wv, nullptr, Vf);

  attn_kernel<<<Bb * Hh * (Ls / 2), 256, 0, stream>>>(Qd, Kd, Vf, attn, Of);

  gemm_nt_f32<<<gemm_grid, 256, 0, stream>>>(Of, Wo, bo, out0);
}

// Round 3
// 5589.328 us; speedup vs baseline: 3.3479x; 3.3479x over previous
//
#include <hip/hip_runtime.h>
#include <math.h>

#define Bb 4
#define Ls 2048
#define Dd 1024
#define Hh 16
#define HDm 64
#define ML (Bb*Ls)   /* 8192 rows */

// ---------------------------------------------------------------------------
// NT GEMM, fp64 accumulate, fp64 output: C[m,n] = sum_k A[m,k]*B[n,k]
// fp64 needed: logits sigma~1.1e6; argmax vs fp64 reference needs abs logit
// error << top-2 gap; fp32 projections give ~4e3 error -> fail.
// ---------------------------------------------------------------------------
__global__ __launch_bounds__(256) void gemm_nt_f64(
    const float* __restrict__ A, const float* __restrict__ B,
    double* __restrict__ C) {
  const int N = Dd, K = Dd;
  __shared__ float As[64][17];
  __shared__ float Bs[64][17];
  int tid = threadIdx.x;
  int tx = tid & 15, ty = tid >> 4;
  int bm = blockIdx.y * 64, bn = blockIdx.x * 64;
  double acc[4][4];
#pragma unroll
  for (int i = 0; i < 4; i++)
#pragma unroll
    for (int j = 0; j < 4; j++) acc[i][j] = 0.0;

  for (int k0 = 0; k0 < K; k0 += 16) {
#pragma unroll
    for (int i = 0; i < 4; i++) {
      int idx = tid + i * 256;
      int r = idx >> 4, c = idx & 15;
      As[r][c] = A[(size_t)(bm + r) * K + k0 + c];
      Bs[r][c] = B[(size_t)(bn + r) * K + k0 + c];
    }
    __syncthreads();
#pragma unroll
    for (int kk = 0; kk < 16; kk++) {
      double a[4], b[4];
#pragma unroll
      for (int i = 0; i < 4; i++) a[i] = (double)As[ty * 4 + i][kk];
#pragma unroll
      for (int j = 0; j < 4; j++) b[j] = (double)Bs[tx * 4 + j][kk];
#pragma unroll
      for (int i = 0; i < 4; i++)
#pragma unroll
        for (int j = 0; j < 4; j++)
          acc[i][j] = fma(a[i], b[j], acc[i][j]);
    }
    __syncthreads();
  }
#pragma unroll
  for (int i = 0; i < 4; i++) {
    size_t m = (size_t)(bm + ty * 4 + i);
#pragma unroll
    for (int j = 0; j < 4; j++) {
      int n = bn + tx * 4 + j;
      C[m * N + n] = acc[i][j];
    }
  }
}

// ---------------------------------------------------------------------------
// NT GEMM, fp32, optional bias
// ---------------------------------------------------------------------------
__global__ __launch_bounds__(256) void gemm_nt_f32(
    const float* __restrict__ A, const float* __restrict__ B,
    const float* __restrict__ bias, float* __restrict__ C) {
  const int N = Dd, K = Dd;
  __shared__ float As[64][17];
  __shared__ float Bs[64][17];
  int tid = threadIdx.x;
  int tx = tid & 15, ty = tid >> 4;
  int bm = blockIdx.y * 64, bn = blockIdx.x * 64;
  float acc[4][4];
#pragma unroll
  for (int i = 0; i < 4; i++)
#pragma unroll
    for (int j = 0; j < 4; j++) acc[i][j] = 0.0f;

  for (int k0 = 0; k0 < K; k0 += 16) {
#pragma unroll
    for (int i = 0; i < 4; i++) {
      int idx = tid + i * 256;
      int r = idx >> 4, c = idx & 15;
      As[r][c] = A[(size_t)(bm + r) * K + k0 + c];
      Bs[r][c] = B[(size_t)(bn + r) * K + k0 + c];
    }
    __syncthreads();
#pragma unroll
    for (int kk = 0; kk < 16; kk++) {
      float a[4], b[4];
#pragma unroll
      for (int i = 0; i < 4; i++) a[i] = As[ty * 4 + i][kk];
#pragma unroll
      for (int j = 0; j < 4; j++) b[j] = Bs[tx * 4 + j][kk];
#pragma unroll
      for (int i = 0; i < 4; i++)
#pragma unroll
        for (int j = 0; j < 4; j++)
          acc[i][j] = fmaf(a[i], b[j], acc[i][j]);
    }
    __syncthreads();
  }
#pragma unroll
  for (int i = 0; i < 4; i++) {
    size_t m = (size_t)(bm + ty * 4 + i);
#pragma unroll
    for (int j = 0; j < 4; j++) {
      int n = bn + tx * 4 + j;
      float v = acc[i][j];
      if (bias) v += bias[n];
      C[m * N + n] = v;
    }
  }
}

// ---------------------------------------------------------------------------
// One-sweep flash attention. Block = (b, h, 64 q rows), K/V tiles of 32 keys.
// Per thread: 4 rows (ty) x 2 keys (tx), fp64 logits from LDS.
// Online softmax with FLOAT-ROUNDED running max "ref" used consistently as
// the exponent reference (|m| < 2^23 -> p~ <= e^0.25, rounding cancels when
// attn_scale re-applies the same stored float). Unnormalized p~ written to
// attn; per-(row,tile) ref + final ref + sum stashed in the DEAD column
// slice of Qd this block owns (Q lives in LDS after the first barrier).
// Stats in registers (rows wave-private, xor-butterfly all-reduce); PV via
// __shfl broadcast of p~ (no P staging in LDS).
// LDS: Qs 33792 + Ks 16896 + Vs 8448 = 59136 B -> 2 blocks/CU.
// ---------------------------------------------------------------------------
__global__ __launch_bounds__(256) void attn_flash(
    double* __restrict__ Qd, const double* __restrict__ Kd,
    const float* __restrict__ Vf, float* __restrict__ attn,
    float* __restrict__ O) {
  __shared__ double Qs[64 * 66];
  __shared__ double Ks[32 * 66];
  __shared__ float  Vs[32 * 66];

  const int tid = threadIdx.x;
  const int tx = tid & 15, ty = tid >> 4;
  const int lane = tid & 63;
  const int blk = blockIdx.x;
  const int qt = blk & 31;
  const int h = (blk >> 5) & 15;
  const int b = blk >> 9;
  const int l0 = qt * 64;

  const double* Qg = Qd + ((size_t)(b * Ls + l0)) * Dd + h * HDm;
  const double* Kg = Kd + ((size_t)b * Ls) * Dd + h * HDm;
  const float*  Vg = Vf + ((size_t)b * Ls) * Dd + h * HDm;
  float* aout = attn + ((size_t)((b * Hh + h) * Ls + l0)) * Ls;

  // load Q tile (64x64 fp64), once
#pragma unroll
  for (int t = 0; t < 8; t++) {
    int idx = tid + t * 256;
    int r = idx >> 5, c2 = idx & 31;
    double2 v = *(const double2*)(Qg + (size_t)r * Dd + c2 * 2);
    *(double2*)(&Qs[r * 66 + c2 * 2]) = v;
  }

  double mref[4], sacc[4];
  float Oacc[4][4];
#pragma unroll
  for (int i = 0; i < 4; i++) {
    mref[i] = -INFINITY;
    sacc[i] = 0.0;
#pragma unroll
    for (int j = 0; j < 4; j++) Oacc[i][j] = 0.0f;
  }

  for (int kt = 0; kt < 64; kt++) {
    __syncthreads();  // prior tile's readers done (also covers Q load at kt=0)
#pragma unroll
    for (int t = 0; t < 4; t++) {
      int idx = tid + t * 256;
      int r = idx >> 5, c2 = idx & 31;
      double2 kv = *(const double2*)(Kg + (size_t)(kt * 32 + r) * Dd + c2 * 2);
      *(double2*)(&Ks[r * 66 + c2 * 2]) = kv;
      float2 vv = *(const float2*)(Vg + (size_t)(kt * 32 + r) * Dd + c2 * 2);
      *(float2*)(&Vs[r * 66 + c2 * 2]) = vv;
    }
    __syncthreads();

    // fp64 logits: 4 rows x 2 keys
    double e[4][2];
#pragma unroll
    for (int i = 0; i < 4; i++) { e[i][0] = 0.0; e[i][1] = 0.0; }
#pragma unroll 8
    for (int kk2 = 0; kk2 < 32; kk2++) {
      double2 q[4], k[2];
#pragma unroll
      for (int i = 0; i < 4; i++)
        q[i] = *(const double2*)(&Qs[(ty * 4 + i) * 66 + kk2 * 2]);
#pragma unroll
      for (int j = 0; j < 2; j++)
        k[j] = *(const double2*)(&Ks[(tx * 2 + j) * 66 + kk2 * 2]);
#pragma unroll
      for (int i = 0; i < 4; i++)
#pragma unroll
        for (int j = 0; j < 2; j++)
          e[i][j] = fma(q[i].y, k[j].y, fma(q[i].x, k[j].x, e[i][j]));
    }

    // online update per row (wave-private 16-lane groups)
    float pf[4][2];
#pragma unroll
    for (int i = 0; i < 4; i++) {
      e[i][0] *= 0.125; e[i][1] *= 0.125;
      double tmax = fmax(e[i][0], e[i][1]);
#pragma unroll
      for (int m = 1; m < 16; m <<= 1) tmax = fmax(tmax, __shfl_xor(tmax, m));
      double mo = mref[i];
      double mn_raw = fmax(mo, tmax);
      double ref = (double)(float)mn_raw;   // float-rounded reference
      float p0 = expf((float)(e[i][0] - ref));
      float p1 = expf((float)(e[i][1] - ref));
      double ts = (double)p0 + (double)p1;
#pragma unroll
      for (int m = 1; m < 16; m <<= 1) ts += __shfl_xor(ts, m);
      float factor = expf((float)(mo - ref));  // <= 1 (ref >= mo since mo is float-valued)
      sacc[i] = sacc[i] * (double)factor + ts;
      mref[i] = ref;
      pf[i][0] = p0; pf[i][1] = p1;
#pragma unroll
      for (int j = 0; j < 4; j++) Oacc[i][j] *= factor;
      // unnormalized probs out
      *(float2*)(aout + (size_t)(ty * 4 + i) * Ls + kt * 32 + tx * 2) =
          make_float2(p0, p1);
      // stash this tile's reference (dead Qd slice, only this block touches it)
      if (tx == 0) {
        float* mrow = (float*)(Qd + ((size_t)(b * Ls + l0 + ty * 4 + i)) * Dd + h * HDm);
        mrow[kt] = (float)ref;
      }
    }

    // PV: O[row][c] += p~[row][key] * V[key][c], p~ broadcast via shuffles
#pragma unroll 8
    for (int kk = 0; kk < 32; kk++) {
      int src = (lane & 48) | (kk >> 1);
      float pb[4];
#pragma unroll
      for (int i = 0; i < 4; i++)
        pb[i] = __shfl((kk & 1) ? pf[i][1] : pf[i][0], src);
      float2 v0 = *(const float2*)(&Vs[kk * 66 + tx * 4]);
      float2 v1 = *(const float2*)(&Vs[kk * 66 + tx * 4 + 2]);
#pragma unroll
      for (int i = 0; i < 4; i++) {
        Oacc[i][0] = fmaf(pb[i], v0.x, Oacc[i][0]);
        Oacc[i][1] = fmaf(pb[i], v0.y, Oacc[i][1]);
        Oacc[i][2] = fmaf(pb[i], v1.x, Oacc[i][2]);
        Oacc[i][3] = fmaf(pb[i], v1.y, Oacc[i][3]);
      }
    }
  }

  // epilogue: normalize O, stash final ref + sum per row
#pragma unroll
  for (int i = 0; i < 4; i++) {
    float sv = (float)(1.0 / sacc[i]);
    float4 w = make_float4(Oacc[i][0] * sv, Oacc[i][1] * sv,
                           Oacc[i][2] * sv, Oacc[i][3] * sv);
    *(float4*)(O + ((size_t)(b * Ls + l0 + ty * 4 + i)) * Dd + h * HDm + tx * 4) = w;
    if (tx == 0) {
      float* mrow = (float*)(Qd + ((size_t)(b * Ls + l0 + ty * 4 + i)) * Dd + h * HDm);
      mrow[64] = (float)mref[i];
      *(double*)(mrow + 66) = sacc[i];
    }
  }
}

// ---------------------------------------------------------------------------
// Rescale: p = p~ * exp(ref_t - ref_final) / s. One block per attention row.
// ---------------------------------------------------------------------------
__global__ __launch_bounds__(256) void attn_scale(
    float* __restrict__ attn, const double* __restrict__ Qd) {
  int R = blockIdx.x;                 // 0..131071: ((b*Hh+h)*Ls + l)
  int b = R >> 15;
  int rem = R & 32767;
  int h = rem >> 11;
  int l = rem & 2047;
  const float* mrow = (const float*)(Qd + ((size_t)(b * Ls + l)) * Dd + h * HDm);
  int tid = threadIdx.x;
  int kt = tid >> 2;                  // 8 cols per thread, all within one 32-col tile
  double mt = (double)mrow[kt];
  double mf = (double)mrow[64];
  double s = *(const double*)(mrow + 66);
  float sc = (float)(exp(mt - mf) / s);
  float4* ap = (float4*)(attn + (size_t)R * Ls + tid * 8);
  float4 a0 = ap[0], a1 = ap[1];
  a0.x *= sc; a0.y *= sc; a0.z *= sc; a0.w *= sc;
  a1.x *= sc; a1.y *= sc; a1.z *= sc; a1.w *= sc;
  ap[0] = a0; ap[1] = a1;
}

// ---------------------------------------------------------------------------
extern "C" void kernel_launch(void* const* d_in, const int* in_sizes, int n_in,
                              void* d_out, int out_size, void* d_ws, size_t ws_size,
                              hipStream_t stream) {
  const float* query = (const float*)d_in[0];
  const float* key   = (const float*)d_in[1];
  const float* value = (const float*)d_in[2];
  const float* Wq    = (const float*)d_in[3];
  const float* Wk    = (const float*)d_in[4];
  const float* Wv    = (const float*)d_in[5];
  const float* Wo    = (const float*)d_in[6];
  const float* bo    = (const float*)d_in[7];

  float* out0 = (float*)d_out;            // [B,L,D]
  float* attn = out0 + (size_t)ML * Dd;   // [B,H,L,L]

  // ws: Qd (64MB f64) | Kd (64MB f64) | Vf (32MB f32) | Of (32MB f32)
  char* ws = (char*)d_ws;
  double* Qd = (double*)ws;
  double* Kd = (double*)(ws + (size_t)ML * Dd * 8);
  float*  Vf = (float*)(ws + (size_t)ML * Dd * 16);
  float*  Of = (float*)(ws + (size_t)ML * Dd * 16 + (size_t)ML * Dd * 4);

  dim3 gemm_grid(Dd / 64, ML / 64);
  gemm_nt_f64<<<gemm_grid, 256, 0, stream>>>(query, Wq, Qd);
  gemm_nt_f64<<<gemm_grid, 256, 0, stream>>>(key,   Wk, Kd);
  gemm_nt_f32<<<gemm_grid, 256, 0, stream>>>(value, Wv, nullptr, Vf);

  attn_flash<<<Bb * Hh * (Ls / 64), 256, 0, stream>>>(Qd, Kd, Vf, attn, Of);
  attn_scale<<<Bb * Hh * Ls, 256, 0, stream>>>(attn, Qd);

  gemm_nt_f32<<<gemm_grid, 256, 0, stream>>>(Of, Wo, bo, out0);
}

// Round 4
// 5494.327 us; speedup vs baseline: 3.4058x; 1.0173x over previous
//
#include <hip/hip_runtime.h>
#include <math.h>

#define Bb 4
#define Ls 2048
#define Dd 1024
#define Hh 16
#define HDm 64
#define ML (Bb*Ls)   /* 8192 rows */

// ---------------------------------------------------------------------------
// NT GEMM, fp64 accumulate, fp64 output: C[m,n] = sum_k A[m,k]*B[n,k]
// fp64 needed: logits sigma~1.1e6; argmax vs fp64 reference needs abs logit
// error << top-2 gap; fp32 projections give ~4e3 error -> fail.
// ---------------------------------------------------------------------------
__global__ __launch_bounds__(256) void gemm_nt_f64(
    const float* __restrict__ A, const float* __restrict__ B,
    double* __restrict__ C) {
  const int N = Dd, K = Dd;
  __shared__ float As[64][17];
  __shared__ float Bs[64][17];
  int tid = threadIdx.x;
  int tx = tid & 15, ty = tid >> 4;
  int bm = blockIdx.y * 64, bn = blockIdx.x * 64;
  double acc[4][4];
#pragma unroll
  for (int i = 0; i < 4; i++)
#pragma unroll
    for (int j = 0; j < 4; j++) acc[i][j] = 0.0;

  for (int k0 = 0; k0 < K; k0 += 16) {
#pragma unroll
    for (int i = 0; i < 4; i++) {
      int idx = tid + i * 256;
      int r = idx >> 4, c = idx & 15;
      As[r][c] = A[(size_t)(bm + r) * K + k0 + c];
      Bs[r][c] = B[(size_t)(bn + r) * K + k0 + c];
    }
    __syncthreads();
#pragma unroll
    for (int kk = 0; kk < 16; kk++) {
      double a[4], b[4];
#pragma unroll
      for (int i = 0; i < 4; i++) a[i] = (double)As[ty * 4 + i][kk];
#pragma unroll
      for (int j = 0; j < 4; j++) b[j] = (double)Bs[tx * 4 + j][kk];
#pragma unroll
      for (int i = 0; i < 4; i++)
#pragma unroll
        for (int j = 0; j < 4; j++)
          acc[i][j] = fma(a[i], b[j], acc[i][j]);
    }
    __syncthreads();
  }
#pragma unroll
  for (int i = 0; i < 4; i++) {
    size_t m = (size_t)(bm + ty * 4 + i);
#pragma unroll
    for (int j = 0; j < 4; j++) {
      int n = bn + tx * 4 + j;
      C[m * N + n] = acc[i][j];
    }
  }
}

// ---------------------------------------------------------------------------
// NT GEMM, fp32, optional bias
// ---------------------------------------------------------------------------
__global__ __launch_bounds__(256) void gemm_nt_f32(
    const float* __restrict__ A, const float* __restrict__ B,
    const float* __restrict__ bias, float* __restrict__ C) {
  const int N = Dd, K = Dd;
  __shared__ float As[64][17];
  __shared__ float Bs[64][17];
  int tid = threadIdx.x;
  int tx = tid & 15, ty = tid >> 4;
  int bm = blockIdx.y * 64, bn = blockIdx.x * 64;
  float acc[4][4];
#pragma unroll
  for (int i = 0; i < 4; i++)
#pragma unroll
    for (int j = 0; j < 4; j++) acc[i][j] = 0.0f;

  for (int k0 = 0; k0 < K; k0 += 16) {
#pragma unroll
    for (int i = 0; i < 4; i++) {
      int idx = tid + i * 256;
      int r = idx >> 4, c = idx & 15;
      As[r][c] = A[(size_t)(bm + r) * K + k0 + c];
      Bs[r][c] = B[(size_t)(bn + r) * K + k0 + c];
    }
    __syncthreads();
#pragma unroll
    for (int kk = 0; kk < 16; kk++) {
      float a[4], b[4];
#pragma unroll
      for (int i = 0; i < 4; i++) a[i] = As[ty * 4 + i][kk];
#pragma unroll
      for (int j = 0; j < 4; j++) b[j] = Bs[tx * 4 + j][kk];
#pragma unroll
      for (int i = 0; i < 4; i++)
#pragma unroll
        for (int j = 0; j < 4; j++)
          acc[i][j] = fmaf(a[i], b[j], acc[i][j]);
    }
    __syncthreads();
  }
#pragma unroll
  for (int i = 0; i < 4; i++) {
    size_t m = (size_t)(bm + ty * 4 + i);
#pragma unroll
    for (int j = 0; j < 4; j++) {
      int n = bn + tx * 4 + j;
      float v = acc[i][j];
      if (bias) v += bias[n];
      C[m * N + n] = v;
    }
  }
}

// ---------------------------------------------------------------------------
// One-sweep flash attention, v2.
// Block = (b, h, 32 q rows); K/V tiles of 32 keys; 256 threads (tx16 x ty16).
// Thread tile: rows {ty, ty+16} x keys {tx, tx+16} — INTERLEAVED so LDS
// row-stride per lane is 1 row = 132 words === 4 (mod 32) -> 2-way bank
// aliasing only (free, m136). Round 3's blocked keys gave 4-way (2e8 confl).
// LDS: Qs 16896 + Ks 16896 + Vs 8704 = 42496 B -> 3 blocks/CU (12 waves)
// for barrier overlap (round 3 had 2 blocks, 38% VALUBusy).
// Online softmax with float-rounded running ref (exact-cancel with
// attn_scale); unnormalized p~ to attn; per-(row,tile) ref + final ref +
// sum stashed in the dead column slice of Qd this block owns.
// ---------------------------------------------------------------------------
__global__ __launch_bounds__(256) void attn_flash(
    double* __restrict__ Qd, const double* __restrict__ Kd,
    const float* __restrict__ Vf, float* __restrict__ attn,
    float* __restrict__ O) {
  __shared__ double Qs[32 * 66];
  __shared__ double Ks[32 * 66];
  __shared__ float  Vs[32 * 68];

  const int tid = threadIdx.x;
  const int tx = tid & 15, ty = tid >> 4;
  const int lane = tid & 63;
  const int blk = blockIdx.x;
  const int qt = blk & 63;              // 64 q-tiles of 32 rows
  const int h = (blk >> 6) & 15;
  const int b = blk >> 10;
  const int l0 = qt * 32;

  const double* Qg = Qd + ((size_t)(b * Ls + l0)) * Dd + h * HDm;
  const double* Kg = Kd + ((size_t)b * Ls) * Dd + h * HDm;
  const float*  Vg = Vf + ((size_t)b * Ls) * Dd + h * HDm;
  float* aout = attn + ((size_t)((b * Hh + h) * Ls + l0)) * Ls;

  // load Q tile (32x64 fp64), once
#pragma unroll
  for (int t = 0; t < 4; t++) {
    int idx = tid + t * 256;
    int r = idx >> 5, c2 = idx & 31;
    double2 v = *(const double2*)(Qg + (size_t)r * Dd + c2 * 2);
    *(double2*)(&Qs[r * 66 + c2 * 2]) = v;
  }

  double mref[2], sacc[2];
  float Oacc[2][4];
#pragma unroll
  for (int i = 0; i < 2; i++) {
    mref[i] = -INFINITY;
    sacc[i] = 0.0;
#pragma unroll
    for (int j = 0; j < 4; j++) Oacc[i][j] = 0.0f;
  }

  for (int kt = 0; kt < 64; kt++) {
    __syncthreads();  // prior tile's readers done (covers Q load at kt=0)
#pragma unroll
    for (int t = 0; t < 4; t++) {
      int idx = tid + t * 256;
      int r = idx >> 5, c2 = idx & 31;
      double2 kv = *(const double2*)(Kg + (size_t)(kt * 32 + r) * Dd + c2 * 2);
      *(double2*)(&Ks[r * 66 + c2 * 2]) = kv;
      float2 vv = *(const float2*)(Vg + (size_t)(kt * 32 + r) * Dd + c2 * 2);
      *(float2*)(&Vs[r * 68 + c2 * 2]) = vv;
    }
    __syncthreads();

    // fp64 logits: rows {ty, ty+16} x keys {tx, tx+16}
    double e[2][2];
    e[0][0] = 0.0; e[0][1] = 0.0; e[1][0] = 0.0; e[1][1] = 0.0;
#pragma unroll 8
    for (int kk2 = 0; kk2 < 32; kk2++) {
      double2 q0 = *(const double2*)(&Qs[ty * 66 + kk2 * 2]);
      double2 q1 = *(const double2*)(&Qs[(ty + 16) * 66 + kk2 * 2]);
      double2 k0 = *(const double2*)(&Ks[tx * 66 + kk2 * 2]);
      double2 k1 = *(const double2*)(&Ks[(tx + 16) * 66 + kk2 * 2]);
      e[0][0] = fma(q0.y, k0.y, fma(q0.x, k0.x, e[0][0]));
      e[0][1] = fma(q0.y, k1.y, fma(q0.x, k1.x, e[0][1]));
      e[1][0] = fma(q1.y, k0.y, fma(q1.x, k0.x, e[1][0]));
      e[1][1] = fma(q1.y, k1.y, fma(q1.x, k1.x, e[1][1]));
    }

    // online softmax update per row (row owned by this wave's 16 tx lanes)
    float pf[2][2];
#pragma unroll
    for (int i = 0; i < 2; i++) {
      int row = ty + 16 * i;
      e[i][0] *= 0.125; e[i][1] *= 0.125;
      double tmax = fmax(e[i][0], e[i][1]);
#pragma unroll
      for (int m = 1; m < 16; m <<= 1) tmax = fmax(tmax, __shfl_xor(tmax, m));
      double mo = mref[i];
      double ref = (double)(float)fmax(mo, tmax);  // float-rounded reference
      float p0 = expf((float)(e[i][0] - ref));
      float p1 = expf((float)(e[i][1] - ref));
      double ts = (double)p0 + (double)p1;
#pragma unroll
      for (int m = 1; m < 16; m <<= 1) ts += __shfl_xor(ts, m);
      float factor = expf((float)(mo - ref));  // <= 1 (ref >= mo, mo float-valued)
      sacc[i] = sacc[i] * (double)factor + ts;
      mref[i] = ref;
      pf[i][0] = p0; pf[i][1] = p1;
#pragma unroll
      for (int j = 0; j < 4; j++) Oacc[i][j] *= factor;
      // unnormalized probs out (keys tx and tx+16)
      aout[(size_t)row * Ls + kt * 32 + tx] = p0;
      aout[(size_t)row * Ls + kt * 32 + tx + 16] = p1;
      // stash this tile's reference (dead Qd slice, only this block touches)
      if (tx == 0) {
        float* mrow = (float*)(Qd + ((size_t)(b * Ls + l0 + row)) * Dd + h * HDm);
        mrow[kt] = (float)ref;
      }
    }

    // PV: O[row][c] += p~[row][key] * V[key][c]; p~ broadcast via shuffles
#pragma unroll
    for (int t = 0; t < 16; t++) {          // keys 0..15 (slot j=0)
      int src = (lane & 48) | t;
      float pb0 = __shfl(pf[0][0], src);
      float pb1 = __shfl(pf[1][0], src);
      float4 v = *(const float4*)(&Vs[t * 68 + tx * 4]);
      Oacc[0][0] = fmaf(pb0, v.x, Oacc[0][0]);
      Oacc[0][1] = fmaf(pb0, v.y, Oacc[0][1]);
      Oacc[0][2] = fmaf(pb0, v.z, Oacc[0][2]);
      Oacc[0][3] = fmaf(pb0, v.w, Oacc[0][3]);
      Oacc[1][0] = fmaf(pb1, v.x, Oacc[1][0]);
      Oacc[1][1] = fmaf(pb1, v.y, Oacc[1][1]);
      Oacc[1][2] = fmaf(pb1, v.z, Oacc[1][2]);
      Oacc[1][3] = fmaf(pb1, v.w, Oacc[1][3]);
    }
#pragma unroll
    for (int t = 0; t < 16; t++) {          // keys 16..31 (slot j=1)
      int src = (lane & 48) | t;
      float pb0 = __shfl(pf[0][1], src);
      float pb1 = __shfl(pf[1][1], src);
      float4 v = *(const float4*)(&Vs[(16 + t) * 68 + tx * 4]);
      Oacc[0][0] = fmaf(pb0, v.x, Oacc[0][0]);
      Oacc[0][1] = fmaf(pb0, v.y, Oacc[0][1]);
      Oacc[0][2] = fmaf(pb0, v.z, Oacc[0][2]);
      Oacc[0][3] = fmaf(pb0, v.w, Oacc[0][3]);
      Oacc[1][0] = fmaf(pb1, v.x, Oacc[1][0]);
      Oacc[1][1] = fmaf(pb1, v.y, Oacc[1][1]);
      Oacc[1][2] = fmaf(pb1, v.z, Oacc[1][2]);
      Oacc[1][3] = fmaf(pb1, v.w, Oacc[1][3]);
    }
  }

  // epilogue: normalize O, stash final ref + sum per row
#pragma unroll
  for (int i = 0; i < 2; i++) {
    int row = ty + 16 * i;
    float sv = (float)(1.0 / sacc[i]);
    float4 w = make_float4(Oacc[i][0] * sv, Oacc[i][1] * sv,
                           Oacc[i][2] * sv, Oacc[i][3] * sv);
    *(float4*)(O + ((size_t)(b * Ls + l0 + row)) * Dd + h * HDm + tx * 4) = w;
    if (tx == 0) {
      float* mrow = (float*)(Qd + ((size_t)(b * Ls + l0 + row)) * Dd + h * HDm);
      mrow[64] = (float)mref[i];
      *(double*)(mrow + 66) = sacc[i];
    }
  }
}

// ---------------------------------------------------------------------------
// Rescale: p = p~ * exp(ref_t - ref_final) / s. One block per attention row.
// ---------------------------------------------------------------------------
__global__ __launch_bounds__(256) void attn_scale(
    float* __restrict__ attn, const double* __restrict__ Qd) {
  int R = blockIdx.x;                 // 0..131071: ((b*Hh+h)*Ls + l)
  int b = R >> 15;
  int rem = R & 32767;
  int h = rem >> 11;
  int l = rem & 2047;
  const float* mrow = (const float*)(Qd + ((size_t)(b * Ls + l)) * Dd + h * HDm);
  int tid = threadIdx.x;
  int kt = tid >> 2;                  // 8 cols per thread, within one 32-col tile
  double mt = (double)mrow[kt];
  double mf = (double)mrow[64];
  double s = *(const double*)(mrow + 66);
  float sc = (float)(exp(mt - mf) / s);
  float4* ap = (float4*)(attn + (size_t)R * Ls + tid * 8);
  float4 a0 = ap[0], a1 = ap[1];
  a0.x *= sc; a0.y *= sc; a0.z *= sc; a0.w *= sc;
  a1.x *= sc; a1.y *= sc; a1.z *= sc; a1.w *= sc;
  ap[0] = a0; ap[1] = a1;
}

// ---------------------------------------------------------------------------
extern "C" void kernel_launch(void* const* d_in, const int* in_sizes, int n_in,
                              void* d_out, int out_size, void* d_ws, size_t ws_size,
                              hipStream_t stream) {
  const float* query = (const float*)d_in[0];
  const float* key   = (const float*)d_in[1];
  const float* value = (const float*)d_in[2];
  const float* Wq    = (const float*)d_in[3];
  const float* Wk    = (const float*)d_in[4];
  const float* Wv    = (const float*)d_in[5];
  const float* Wo    = (const float*)d_in[6];
  const float* bo    = (const float*)d_in[7];

  float* out0 = (float*)d_out;            // [B,L,D]
  float* attn = out0 + (size_t)ML * Dd;   // [B,H,L,L]

  // ws: Qd (64MB f64) | Kd (64MB f64) | Vf (32MB f32) | Of (32MB f32)
  char* ws = (char*)d_ws;
  double* Qd = (double*)ws;
  double* Kd = (double*)(ws + (size_t)ML * Dd * 8);
  float*  Vf = (float*)(ws + (size_t)ML * Dd * 16);
  float*  Of = (float*)(ws + (size_t)ML * Dd * 16 + (size_t)ML * Dd * 4);

  dim3 gemm_grid(Dd / 64, ML / 64);
  gemm_nt_f64<<<gemm_grid, 256, 0, stream>>>(query, Wq, Qd);
  gemm_nt_f64<<<gemm_grid, 256, 0, stream>>>(key,   Wk, Kd);
  gemm_nt_f32<<<gemm_grid, 256, 0, stream>>>(value, Wv, nullptr, Vf);

  attn_flash<<<Bb * Hh * (Ls / 32), 256, 0, stream>>>(Qd, Kd, Vf, attn, Of);
  attn_scale<<<Bb * Hh * Ls, 256, 0, stream>>>(attn, Qd);

  gemm_nt_f32<<<gemm_grid, 256, 0, stream>>>(Of, Wo, bo, out0);
}